// Round 6
// baseline (195.866 us; speedup 1.0000x reference)
//
#include <hip/hip_runtime.h>
#include <math.h>

typedef unsigned short u16;
typedef __attribute__((ext_vector_type(8))) short short8;
typedef __attribute__((ext_vector_type(4))) float f32x4;

static __device__ __forceinline__ u16 f2bf(float f) {
  union { float f; unsigned u; } v; v.f = f;
  unsigned u = v.u;
  return (u16)((u + 0x7FFFu + ((u >> 16) & 1u)) >> 16);
}
static __device__ __forceinline__ float bf2f(u16 u) {
  union { unsigned u; float f; } v; v.u = ((unsigned)u) << 16;
  return v.f;
}
static __device__ __forceinline__ f32x4 mfma16(short8 a, short8 b, f32x4 c) {
  return __builtin_amdgcn_mfma_f32_16x16x32_bf16(a, b, c, 0, 0, 0);
}

// ---------------------------------------------------------------------------
// prep: WtV/outwT bf16 transposed [n][k]; Wcat f32 (256x288) + bcat.
// ---------------------------------------------------------------------------
__global__ void prep_weights(const float* __restrict__ vw,
                             const float* __restrict__ offw, const float* __restrict__ attnw,
                             const float* __restrict__ offb, const float* __restrict__ attnb,
                             const float* __restrict__ outw,
                             u16* __restrict__ WtV, u16* __restrict__ outwT,
                             float* __restrict__ Wcat, float* __restrict__ bcat) {
  int idx = blockIdx.x * 256 + threadIdx.x;  // grid 288 -> 73728
  if (idx < 65536) {
    int n = idx >> 8, k = idx & 255;
    WtV[idx] = f2bf(vw[k * 256 + n]);
    outwT[idx] = f2bf(outw[k * 256 + n]);
  }
  if (idx < 73728) {
    int kk = idx / 288, nn = idx % 288;
    Wcat[idx] = (nn < 192) ? offw[kk * 192 + nn] : attnw[kk * 96 + (nn - 192)];
  }
  if (idx < 288) bcat[idx] = (idx < 192) ? offb[idx] : attnb[idx - 192];
}

// ---------------------------------------------------------------------------
// Value GEMM, barrier-free streaming K-loop: each wave owns a 64x128 strip.
// A as 2x float4 + convert, B as short8 (L1/L2-hot). Epilogue: LDS repack
// (syncthreads between write/read as ordering insurance) -> dwordx4 stores.
// ---------------------------------------------------------------------------
__global__ __launch_bounds__(256) void gemm_value_stream(
    const float* __restrict__ A, const u16* __restrict__ Wt,
    const float* __restrict__ bias, u16* __restrict__ C) {
  __shared__ u16 cbuf[4][64 * 128];
  const int tid = threadIdx.x, lane = tid & 63, w = tid >> 6;
  const int m0 = (blockIdx.x * 2 + (w >> 1)) * 64;
  const int n0 = (w & 1) * 128;
  const int r16 = lane & 15, kq = lane >> 4, kh8 = kq * 8;

  f32x4 acc[4][8];
#pragma unroll
  for (int i = 0; i < 4; i++)
#pragma unroll
    for (int j = 0; j < 8; j++) acc[i][j] = (f32x4){0.f, 0.f, 0.f, 0.f};

  const float* ab = A + (size_t)(m0 + r16) * 256 + kh8;
  const u16* bb = Wt + (size_t)(n0 + r16) * 256 + kh8;

#pragma unroll 2
  for (int ks = 0; ks < 8; ks++) {
    const int kk = ks * 32;
    short8 bfr[8];
#pragma unroll
    for (int j = 0; j < 8; j++)
      bfr[j] = *(const short8*)(bb + (size_t)(j * 16) * 256 + kk);
    short8 afr[4];
#pragma unroll
    for (int i = 0; i < 4; i++) {
      const float* ap = ab + (size_t)(i * 16) * 256 + kk;
      float4 lo = *(const float4*)ap;
      float4 hi = *(const float4*)(ap + 4);
      short8 t;
      t[0] = (short)f2bf(lo.x); t[1] = (short)f2bf(lo.y);
      t[2] = (short)f2bf(lo.z); t[3] = (short)f2bf(lo.w);
      t[4] = (short)f2bf(hi.x); t[5] = (short)f2bf(hi.y);
      t[6] = (short)f2bf(hi.z); t[7] = (short)f2bf(hi.w);
      afr[i] = t;
    }
#pragma unroll
    for (int i = 0; i < 4; i++)
#pragma unroll
      for (int j = 0; j < 8; j++)
        acc[i][j] = mfma16(afr[i], bfr[j], acc[i][j]);
  }

  u16* cb = cbuf[w];
#pragma unroll
  for (int i = 0; i < 4; i++)
#pragma unroll
    for (int j = 0; j < 8; j++) {
      const int col = j * 16 + r16;
      const float bc = bias[n0 + col];
#pragma unroll
      for (int r = 0; r < 4; r++) {
        const int row = i * 16 + kq * 4 + r;
        cb[row * 128 + (col ^ ((row & 7) << 3))] = f2bf(acc[i][j][r] + bc);
      }
    }
  __syncthreads();  // ordering insurance for LDS write->read
#pragma unroll
  for (int it = 0; it < 16; it++) {
    const int row = it * 4 + kq;
    const int cg = r16 * 8;
    *(short8*)(C + (size_t)(m0 + row) * 256 + n0 + cg) =
        *(const short8*)&cb[row * 128 + (cg ^ ((row & 7) << 3))];
  }
}

// ---------------------------------------------------------------------------
// Out-proj streaming GEMM: A bf16 (4864 rows padded), C f32 (4800,256).
// ---------------------------------------------------------------------------
__global__ __launch_bounds__(256) void gemm_out_stream(
    const u16* __restrict__ A, const u16* __restrict__ Wt,
    const float* __restrict__ bias, float* __restrict__ C) {
  const int tid = threadIdx.x, lane = tid & 63, w = tid >> 6;
  const int m0 = (blockIdx.x * 2 + (w >> 1)) * 64;
  const int n0 = (w & 1) * 128;
  const int r16 = lane & 15, kq = lane >> 4, kh8 = kq * 8;

  f32x4 acc[4][8];
#pragma unroll
  for (int i = 0; i < 4; i++)
#pragma unroll
    for (int j = 0; j < 8; j++) acc[i][j] = (f32x4){0.f, 0.f, 0.f, 0.f};

  const u16* ab = A + (size_t)(m0 + r16) * 256 + kh8;
  const u16* bb = Wt + (size_t)(n0 + r16) * 256 + kh8;

#pragma unroll 2
  for (int ks = 0; ks < 8; ks++) {
    const int kk = ks * 32;
    short8 bfr[8], afr[4];
#pragma unroll
    for (int j = 0; j < 8; j++)
      bfr[j] = *(const short8*)(bb + (size_t)(j * 16) * 256 + kk);
#pragma unroll
    for (int i = 0; i < 4; i++)
      afr[i] = *(const short8*)(ab + (size_t)(i * 16) * 256 + kk);
#pragma unroll
    for (int i = 0; i < 4; i++)
#pragma unroll
      for (int j = 0; j < 8; j++)
        acc[i][j] = mfma16(afr[i], bfr[j], acc[i][j]);
  }

  if (m0 >= 4800) return;
#pragma unroll
  for (int i = 0; i < 4; i++)
#pragma unroll
    for (int j = 0; j < 8; j++) {
      const int col = n0 + j * 16 + r16;
      const float bc = bias[col];
#pragma unroll
      for (int r = 0; r < 4; r++) {
        const int row = m0 + i * 16 + kq * 4 + r;
        C[(size_t)row * 256 + col] = acc[i][j][r] + bc;
      }
    }
}

// ---------------------------------------------------------------------------
// fp32 GEMM for position-critical offsets/logits (verified R1/R4 kernel).
// ---------------------------------------------------------------------------
#define BM 128
#define BN 128
#define BK 8
#define TM 8
#define TN 8
__global__ __launch_bounds__(256) void gemm_f32(
    const float* __restrict__ A, const float* __restrict__ W,
    const float* __restrict__ bias, float* __restrict__ C,
    int M, int N, int K) {
  __shared__ float As[BK][BM + 4];
  __shared__ float Bs[BK][BN + 4];
  const int tid = threadIdx.x;
  const int bm = blockIdx.y, bn = blockIdx.x;
  const int tr = tid >> 4, tc = tid & 15;

  float acc[TM][TN];
#pragma unroll
  for (int i = 0; i < TM; i++)
#pragma unroll
    for (int j = 0; j < TN; j++) acc[i][j] = 0.f;

  int arow = bm * BM + (tid >> 1);
  int arow_c = arow < M ? arow : (M - 1);
  const float* Aptr = A + (size_t)arow_c * K + ((tid & 1) << 2);
  int bcol = bn * BN + ((tid & 31) << 2);
  const bool bvalid = bcol < N;
  const float* Wptr = W + (size_t)(tid >> 5) * N + bcol;

  for (int k0 = 0; k0 < K; k0 += BK) {
    float4 av = *(const float4*)(Aptr + k0);
    float4 bv = bvalid ? *(const float4*)(Wptr + (size_t)k0 * N)
                       : make_float4(0.f, 0.f, 0.f, 0.f);
    __syncthreads();
    As[(tid & 1) * 4 + 0][tid >> 1] = av.x;
    As[(tid & 1) * 4 + 1][tid >> 1] = av.y;
    As[(tid & 1) * 4 + 2][tid >> 1] = av.z;
    As[(tid & 1) * 4 + 3][tid >> 1] = av.w;
    *(float4*)&Bs[tid >> 5][(tid & 31) << 2] = bv;
    __syncthreads();
#pragma unroll
    for (int k = 0; k < BK; k++) {
      float ar[TM], br[TN];
      *(float4*)&ar[0] = *(const float4*)&As[k][tr * TM];
      *(float4*)&ar[4] = *(const float4*)&As[k][tr * TM + 4];
      *(float4*)&br[0] = *(const float4*)&Bs[k][tc * TN];
      *(float4*)&br[4] = *(const float4*)&Bs[k][tc * TN + 4];
#pragma unroll
      for (int i = 0; i < TM; i++)
#pragma unroll
        for (int j = 0; j < TN; j++) acc[i][j] = fmaf(ar[i], br[j], acc[i][j]);
    }
  }

#pragma unroll
  for (int i = 0; i < TM; i++) {
    int row = bm * BM + tr * TM + i;
    if (row >= M) continue;
    float* Crow = C + (size_t)row * N;
#pragma unroll
    for (int j = 0; j < TN; j += 4) {
      int col = bn * BN + tc * TN + j;
      if (col < N) {
        float4 o;
        o.x = acc[i][j + 0] + bias[col + 0];
        o.y = acc[i][j + 1] + bias[col + 1];
        o.z = acc[i][j + 2] + bias[col + 2];
        o.w = acc[i][j + 3] + bias[col + 3];
        *(float4*)(Crow + col) = o;
      }
    }
  }
}

// ---------------------------------------------------------------------------
// Branch-free sampling, 8 channels/lane (short8 gathers), 8 queries/block.
// ---------------------------------------------------------------------------
__global__ __launch_bounds__(256) void ms_deform_fused(
    const u16* __restrict__ value,    // (B*8400, 256) bf16
    const float* __restrict__ offaw,  // (4800, 288)
    const float* __restrict__ refp,   // (16,300,3,4)
    u16* __restrict__ attn_out) {     // (4864, 256) bf16
  const int tid = threadIdx.x;
  const int bq = blockIdx.x * 8 + (tid >> 5);  // grid 608 -> 0..4863
  const int h = (tid >> 2) & 7;
  const int d8 = (tid & 3) * 8;
  u16* outp = attn_out + (size_t)bq * 256 + h * 32 + d8;
  if (bq >= 4800) {
    *(short8*)outp = (short8){0, 0, 0, 0, 0, 0, 0, 0};
    return;
  }
  const int b = bq / 300;
  const float* row = offaw + (size_t)bq * 288;

  float lg[12];
#pragma unroll
  for (int j = 0; j < 12; j++) lg[j] = row[192 + h * 12 + j];
  float m = lg[0];
#pragma unroll
  for (int j = 1; j < 12; j++) m = fmaxf(m, lg[j]);
  float s = 0.f;
#pragma unroll
  for (int j = 0; j < 12; j++) { lg[j] = __expf(lg[j] - m); s += lg[j]; }
  const float inv = 1.f / s;

  const int lvlW[3] = {80, 40, 20};
  const int lvlS[3] = {0, 6400, 8000};
  const float* ref = refp + (size_t)bq * 12;
  float acc[8];
#pragma unroll
  for (int e = 0; e < 8; e++) acc[e] = 0.f;

#pragma unroll
  for (int l = 0; l < 3; l++) {
    const int Ws = lvlW[l];
    const float r0 = ref[l * 4 + 0], r1 = ref[l * 4 + 1];
    const float r2 = ref[l * 4 + 2], r3 = ref[l * 4 + 3];
    const u16* vbase = value + ((size_t)(b * 8400 + lvlS[l]) * 256) + h * 32 + d8;
#pragma unroll
    for (int p = 0; p < 4; p++) {
      const float ox = row[h * 24 + l * 8 + p * 2 + 0];
      const float oy = row[h * 24 + l * 8 + p * 2 + 1];
      const float x = (r0 + ox * 0.125f * r2) * (float)Ws - 0.5f;
      const float y = (r1 + oy * 0.125f * r3) * (float)Ws - 0.5f;
      const float x0f = floorf(x), y0f = floorf(y);
      const float wx = x - x0f, wy = y - y0f;
      const int x0 = (int)x0f, y0 = (int)y0f;
      const int x0c = min(max(x0, 0), Ws - 1), x1c = min(max(x0 + 1, 0), Ws - 1);
      const int y0c = min(max(y0, 0), Ws - 1), y1c = min(max(y0 + 1, 0), Ws - 1);
      const float fx0 = ((unsigned)x0 < (unsigned)Ws) ? 1.f : 0.f;
      const float fx1 = ((unsigned)(x0 + 1) < (unsigned)Ws) ? 1.f : 0.f;
      const float fy0 = ((unsigned)y0 < (unsigned)Ws) ? 1.f : 0.f;
      const float fy1 = ((unsigned)(y0 + 1) < (unsigned)Ws) ? 1.f : 0.f;
      const short8 v00 = *(const short8*)(vbase + (size_t)(y0c * Ws + x0c) * 256);
      const short8 v01 = *(const short8*)(vbase + (size_t)(y0c * Ws + x1c) * 256);
      const short8 v10 = *(const short8*)(vbase + (size_t)(y1c * Ws + x0c) * 256);
      const short8 v11 = *(const short8*)(vbase + (size_t)(y1c * Ws + x1c) * 256);
      const float pw = lg[l * 4 + p] * inv;
      const float w00 = (1.f - wx) * (1.f - wy) * fy0 * fx0 * pw;
      const float w01 = wx * (1.f - wy) * fy0 * fx1 * pw;
      const float w10 = (1.f - wx) * wy * fy1 * fx0 * pw;
      const float w11 = wx * wy * fy1 * fx1 * pw;
#pragma unroll
      for (int e = 0; e < 8; e++) {
        acc[e] = fmaf(w00, bf2f((u16)v00[e]), acc[e]);
        acc[e] = fmaf(w01, bf2f((u16)v01[e]), acc[e]);
        acc[e] = fmaf(w10, bf2f((u16)v10[e]), acc[e]);
        acc[e] = fmaf(w11, bf2f((u16)v11[e]), acc[e]);
      }
    }
  }
  short8 o;
#pragma unroll
  for (int e = 0; e < 8; e++) o[e] = (short)f2bf(acc[e]);
  *(short8*)outp = o;
}

extern "C" void kernel_launch(void* const* d_in, const int* in_sizes, int n_in,
                              void* d_out, int out_size, void* d_ws, size_t ws_size,
                              hipStream_t stream) {
  const float* hidden = (const float*)d_in[0];
  const float* ehs    = (const float*)d_in[1];
  const float* refp   = (const float*)d_in[2];
  const float* vw     = (const float*)d_in[3];
  const float* vb     = (const float*)d_in[4];
  const float* offw   = (const float*)d_in[5];
  const float* offb   = (const float*)d_in[6];
  const float* attnw  = (const float*)d_in[7];
  const float* attnb  = (const float*)d_in[8];
  const float* outw   = (const float*)d_in[9];
  const float* outb   = (const float*)d_in[10];
  float* out = (float*)d_out;

  u16* value = (u16*)d_ws;                 // 34406400 u16
  u16* attn  = value + 34406400;           // 1245184 u16
  u16* WtV   = attn + 1245184;             // 65536
  u16* outwT = WtV + 65536;                // 65536
  float* Wcat  = (float*)(outwT + 65536);  // 73728 f32
  float* bcat  = Wcat + 73728;             // 512
  float* offaw = bcat + 512;               // 1382400

  prep_weights<<<288, 256, 0, stream>>>(vw, offw, attnw, offb, attnb, outw,
                                        WtV, outwT, Wcat, bcat);
  gemm_value_stream<<<1050, 256, 0, stream>>>(ehs, WtV, vb, value);
  gemm_f32<<<dim3(3, 38), 256, 0, stream>>>(hidden, Wcat, bcat, offaw, 4800, 288, 256);
  ms_deform_fused<<<608, 256, 0, stream>>>(value, offaw, refp, attn);
  gemm_out_stream<<<38, 256, 0, stream>>>(attn, outwT, outb, out);
}

// Round 7
// 171.902 us; speedup vs baseline: 1.1394x; 1.1394x over previous
//
#include <hip/hip_runtime.h>
#include <math.h>

typedef unsigned short u16;
typedef __attribute__((ext_vector_type(8))) short short8;
typedef __attribute__((ext_vector_type(4))) float f32x4;

static __device__ __forceinline__ u16 f2bf(float f) {
  union { float f; unsigned u; } v; v.f = f;
  unsigned u = v.u;
  return (u16)((u + 0x7FFFu + ((u >> 16) & 1u)) >> 16);
}
static __device__ __forceinline__ float bf2f(u16 u) {
  union { unsigned u; float f; } v; v.u = ((unsigned)u) << 16;
  return v.f;
}
static __device__ __forceinline__ unsigned cvtpk(float lo, float hi) {
  unsigned r;
  asm("v_cvt_pk_bf16_f32 %0, %1, %2" : "=v"(r) : "v"(lo), "v"(hi));
  return r;
}
static __device__ __forceinline__ f32x4 mfma16(short8 a, short8 b, f32x4 c) {
  return __builtin_amdgcn_mfma_f32_16x16x32_bf16(a, b, c, 0, 0, 0);
}

// ---------------------------------------------------------------------------
// prep: WtV/outwT bf16 transposed [n][k]; Wcat f32 (256x288) + bcat.
// ---------------------------------------------------------------------------
__global__ void prep_weights(const float* __restrict__ vw,
                             const float* __restrict__ offw, const float* __restrict__ attnw,
                             const float* __restrict__ offb, const float* __restrict__ attnb,
                             const float* __restrict__ outw,
                             u16* __restrict__ WtV, u16* __restrict__ outwT,
                             float* __restrict__ Wcat, float* __restrict__ bcat) {
  int idx = blockIdx.x * 256 + threadIdx.x;  // grid 288 -> 73728
  if (idx < 65536) {
    int n = idx >> 8, k = idx & 255;
    WtV[idx] = f2bf(vw[k * 256 + n]);
    outwT[idx] = f2bf(outw[k * 256 + n]);
  }
  if (idx < 73728) {
    int kk = idx / 288, nn = idx % 288;
    Wcat[idx] = (nn < 192) ? offw[kk * 192 + nn] : attnw[kk * 96 + (nn - 192)];
  }
  if (idx < 288) bcat[idx] = (idx < 192) ? offb[idx] : attnb[idx - 192];
}

// ---------------------------------------------------------------------------
// Fat kernel: blocks [0,114) = offsets fp32 GEMM; blocks [114,1164) = value GEMM.
//
// Value GEMM: block = 4 waves x (64 rows x 128 cols) = 256x128 tile.
// B panel [128n][256k] bf16 staged ONCE into 64KB LDS via global_load_lds
// (linear dest + inverse-swizzled source; read side applies the same XOR).
// Then a barrier-free K-loop: A fragments straight from global (fp32),
// cvt_pk to bf16 in-reg, MFMA vs LDS B. Epilogue reuses B-LDS as repack buf.
// ---------------------------------------------------------------------------
#define NOFF 114

__global__ __launch_bounds__(256) void fat_gemm(
    const float* __restrict__ ehs, const u16* __restrict__ WtV,
    const float* __restrict__ vbias, u16* __restrict__ value,
    const float* __restrict__ hidden, const float* __restrict__ Wcat,
    const float* __restrict__ bcat, float* __restrict__ offaw) {
  __shared__ __align__(16) u16 Bs[32768];  // 64 KiB
  const int tid = threadIdx.x;

  if (blockIdx.x < NOFF) {
    // ---------------- offsets fp32 GEMM (proven R1 body), M=4800 N=288 K=256
    float* Asf = (float*)Bs;        // [8][132]
    float* Bsf = Asf + 8 * 132;     // [8][132]
    const int rel = blockIdx.x;
    const int bm = rel / 3, bn = rel % 3;
    const int tr = tid >> 4, tc = tid & 15;

    float acc[8][8];
#pragma unroll
    for (int i = 0; i < 8; i++)
#pragma unroll
      for (int j = 0; j < 8; j++) acc[i][j] = 0.f;

    int arow = bm * 128 + (tid >> 1);
    int arow_c = arow < 4800 ? arow : 4799;
    const float* Aptr = hidden + (size_t)arow_c * 256 + ((tid & 1) << 2);
    int bcol = bn * 128 + ((tid & 31) << 2);
    const bool bvalid = bcol < 288;
    const float* Wptr = Wcat + (size_t)(tid >> 5) * 288 + bcol;

    for (int k0 = 0; k0 < 256; k0 += 8) {
      float4 av = *(const float4*)(Aptr + k0);
      float4 bv = bvalid ? *(const float4*)(Wptr + (size_t)k0 * 288)
                         : make_float4(0.f, 0.f, 0.f, 0.f);
      __syncthreads();
      Asf[((tid & 1) * 4 + 0) * 132 + (tid >> 1)] = av.x;
      Asf[((tid & 1) * 4 + 1) * 132 + (tid >> 1)] = av.y;
      Asf[((tid & 1) * 4 + 2) * 132 + (tid >> 1)] = av.z;
      Asf[((tid & 1) * 4 + 3) * 132 + (tid >> 1)] = av.w;
      *(float4*)&Bsf[(tid >> 5) * 132 + ((tid & 31) << 2)] = bv;
      __syncthreads();
#pragma unroll
      for (int k = 0; k < 8; k++) {
        float ar[8], br[8];
        *(float4*)&ar[0] = *(const float4*)&Asf[k * 132 + tr * 8];
        *(float4*)&ar[4] = *(const float4*)&Asf[k * 132 + tr * 8 + 4];
        *(float4*)&br[0] = *(const float4*)&Bsf[k * 132 + tc * 8];
        *(float4*)&br[4] = *(const float4*)&Bsf[k * 132 + tc * 8 + 4];
#pragma unroll
        for (int i = 0; i < 8; i++)
#pragma unroll
          for (int j = 0; j < 8; j++) acc[i][j] = fmaf(ar[i], br[j], acc[i][j]);
      }
    }
#pragma unroll
    for (int i = 0; i < 8; i++) {
      int row = bm * 128 + tr * 8 + i;
      if (row >= 4800) continue;
      float* Crow = offaw + (size_t)row * 288;
#pragma unroll
      for (int j = 0; j < 8; j += 4) {
        int col = bn * 128 + tc * 8 + j;
        if (col < 288) {
          float4 o;
          o.x = acc[i][j + 0] + bcat[col + 0];
          o.y = acc[i][j + 1] + bcat[col + 1];
          o.z = acc[i][j + 2] + bcat[col + 2];
          o.w = acc[i][j + 3] + bcat[col + 3];
          *(float4*)(Crow + col) = o;
        }
      }
    }
    return;
  }

  // ---------------- value GEMM ----------------
  const int vb_id = blockIdx.x - NOFF;        // 0..1049
  const int m0 = (vb_id >> 1) * 256;
  const int n0 = (vb_id & 1) * 128;
  const int w = tid >> 6, lane = tid & 63;
  const int r16 = lane & 15, kq = lane >> 4;

  // Stage B panel: LDS[n*256 + (k ^ ((n&7)*8))] = WtV[n0+n][k]
  // dest linear in tid (wave-uniform base + lane*16B); source inverse-swizzled.
#pragma unroll
  for (int c = 0; c < 16; c++) {
    const int n = c * 8 + (tid >> 5);
    const int ksw = ((tid & 31) ^ (n & 7)) * 8;
    __builtin_amdgcn_global_load_lds(
        (const u16*)(WtV + (size_t)(n0 + n) * 256 + ksw),
        Bs + c * 2048 + w * 512, 16, 0, 0);
  }
  __syncthreads();

  f32x4 acc[4][8];
#pragma unroll
  for (int i = 0; i < 4; i++)
#pragma unroll
    for (int j = 0; j < 8; j++) acc[i][j] = (f32x4){0.f, 0.f, 0.f, 0.f};

  const float* arow = ehs + (size_t)(m0 + w * 64 + r16) * 256;

#pragma unroll
  for (int ks = 0; ks < 8; ks++) {
    const int kk = ks * 32 + kq * 8;  // float index within row
    short8 afr[4];
#pragma unroll
    for (int i = 0; i < 4; i++) {
      const float* ap = arow + (size_t)(i * 16) * 256 + kk;
      float4 lo = *(const float4*)ap;
      float4 hi = *(const float4*)(ap + 4);
      union { unsigned u[4]; short8 s; } t;
      t.u[0] = cvtpk(lo.x, lo.y);
      t.u[1] = cvtpk(lo.z, lo.w);
      t.u[2] = cvtpk(hi.x, hi.y);
      t.u[3] = cvtpk(hi.z, hi.w);
      afr[i] = t.s;
    }
    short8 bfr[8];
#pragma unroll
    for (int j = 0; j < 8; j++) {
      const int n = j * 16 + r16;
      bfr[j] = *(const short8*)&Bs[n * 256 + (kk ^ ((n & 7) * 8))];
    }
#pragma unroll
    for (int i = 0; i < 4; i++)
#pragma unroll
      for (int j = 0; j < 8; j++)
        acc[i][j] = mfma16(afr[i], bfr[j], acc[i][j]);
  }

  // Epilogue: reuse Bs as per-wave repack buffer (64 rows x 128 cols each)
  __syncthreads();  // all waves done reading B
  u16* cb = Bs + w * 8192;
#pragma unroll
  for (int i = 0; i < 4; i++)
#pragma unroll
    for (int j = 0; j < 8; j++) {
      const int col = j * 16 + r16;
      const float bc = vbias[n0 + col];
#pragma unroll
      for (int r = 0; r < 4; r++) {
        const int row = i * 16 + kq * 4 + r;
        cb[row * 128 + (col ^ ((row & 7) << 3))] = f2bf(acc[i][j][r] + bc);
      }
    }
  __syncthreads();  // ordering insurance
#pragma unroll
  for (int it = 0; it < 16; it++) {
    const int row = it * 4 + kq;
    const int cg = r16 * 8;
    *(short8*)(value + (size_t)(m0 + w * 64 + row) * 256 + n0 + cg) =
        *(const short8*)&cb[row * 128 + (cg ^ ((row & 7) << 3))];
  }
}

// ---------------------------------------------------------------------------
// Out-proj streaming GEMM: A bf16 (4864 rows padded), C f32 (4800,256). Proven R6.
// ---------------------------------------------------------------------------
__global__ __launch_bounds__(256) void gemm_out_stream(
    const u16* __restrict__ A, const u16* __restrict__ Wt,
    const float* __restrict__ bias, float* __restrict__ C) {
  const int tid = threadIdx.x, lane = tid & 63, w = tid >> 6;
  const int m0 = (blockIdx.x * 2 + (w >> 1)) * 64;
  const int n0 = (w & 1) * 128;
  const int r16 = lane & 15, kq = lane >> 4, kh8 = kq * 8;

  f32x4 acc[4][8];
#pragma unroll
  for (int i = 0; i < 4; i++)
#pragma unroll
    for (int j = 0; j < 8; j++) acc[i][j] = (f32x4){0.f, 0.f, 0.f, 0.f};

  const u16* ab = A + (size_t)(m0 + r16) * 256 + kh8;
  const u16* bb = Wt + (size_t)(n0 + r16) * 256 + kh8;

#pragma unroll 2
  for (int ks = 0; ks < 8; ks++) {
    const int kk = ks * 32;
    short8 bfr[8], afr[4];
#pragma unroll
    for (int j = 0; j < 8; j++)
      bfr[j] = *(const short8*)(bb + (size_t)(j * 16) * 256 + kk);
#pragma unroll
    for (int i = 0; i < 4; i++)
      afr[i] = *(const short8*)(ab + (size_t)(i * 16) * 256 + kk);
#pragma unroll
    for (int i = 0; i < 4; i++)
#pragma unroll
      for (int j = 0; j < 8; j++)
        acc[i][j] = mfma16(afr[i], bfr[j], acc[i][j]);
  }

  if (m0 >= 4800) return;
#pragma unroll
  for (int i = 0; i < 4; i++)
#pragma unroll
    for (int j = 0; j < 8; j++) {
      const int col = n0 + j * 16 + r16;
      const float bc = bias[col];
#pragma unroll
      for (int r = 0; r < 4; r++) {
        const int row = m0 + i * 16 + kq * 4 + r;
        C[(size_t)row * 256 + col] = acc[i][j][r] + bc;
      }
    }
}

// ---------------------------------------------------------------------------
// Branch-free sampling, 8 channels/lane (short8 gathers), 8 queries/block. Proven R6.
// ---------------------------------------------------------------------------
__global__ __launch_bounds__(256) void ms_deform_fused(
    const u16* __restrict__ value,    // (B*8400, 256) bf16
    const float* __restrict__ offaw,  // (4800, 288)
    const float* __restrict__ refp,   // (16,300,3,4)
    u16* __restrict__ attn_out) {     // (4864, 256) bf16
  const int tid = threadIdx.x;
  const int bq = blockIdx.x * 8 + (tid >> 5);  // grid 608 -> 0..4863
  const int h = (tid >> 2) & 7;
  const int d8 = (tid & 3) * 8;
  u16* outp = attn_out + (size_t)bq * 256 + h * 32 + d8;
  if (bq >= 4800) {
    *(short8*)outp = (short8){0, 0, 0, 0, 0, 0, 0, 0};
    return;
  }
  const int b = bq / 300;
  const float* row = offaw + (size_t)bq * 288;

  float lg[12];
#pragma unroll
  for (int j = 0; j < 12; j++) lg[j] = row[192 + h * 12 + j];
  float m = lg[0];
#pragma unroll
  for (int j = 1; j < 12; j++) m = fmaxf(m, lg[j]);
  float s = 0.f;
#pragma unroll
  for (int j = 0; j < 12; j++) { lg[j] = __expf(lg[j] - m); s += lg[j]; }
  const float inv = 1.f / s;

  const int lvlW[3] = {80, 40, 20};
  const int lvlS[3] = {0, 6400, 8000};
  const float* ref = refp + (size_t)bq * 12;
  float acc[8];
#pragma unroll
  for (int e = 0; e < 8; e++) acc[e] = 0.f;

#pragma unroll
  for (int l = 0; l < 3; l++) {
    const int Ws = lvlW[l];
    const float r0 = ref[l * 4 + 0], r1 = ref[l * 4 + 1];
    const float r2 = ref[l * 4 + 2], r3 = ref[l * 4 + 3];
    const u16* vbase = value + ((size_t)(b * 8400 + lvlS[l]) * 256) + h * 32 + d8;
#pragma unroll
    for (int p = 0; p < 4; p++) {
      const float ox = row[h * 24 + l * 8 + p * 2 + 0];
      const float oy = row[h * 24 + l * 8 + p * 2 + 1];
      const float x = (r0 + ox * 0.125f * r2) * (float)Ws - 0.5f;
      const float y = (r1 + oy * 0.125f * r3) * (float)Ws - 0.5f;
      const float x0f = floorf(x), y0f = floorf(y);
      const float wx = x - x0f, wy = y - y0f;
      const int x0 = (int)x0f, y0 = (int)y0f;
      const int x0c = min(max(x0, 0), Ws - 1), x1c = min(max(x0 + 1, 0), Ws - 1);
      const int y0c = min(max(y0, 0), Ws - 1), y1c = min(max(y0 + 1, 0), Ws - 1);
      const float fx0 = ((unsigned)x0 < (unsigned)Ws) ? 1.f : 0.f;
      const float fx1 = ((unsigned)(x0 + 1) < (unsigned)Ws) ? 1.f : 0.f;
      const float fy0 = ((unsigned)y0 < (unsigned)Ws) ? 1.f : 0.f;
      const float fy1 = ((unsigned)(y0 + 1) < (unsigned)Ws) ? 1.f : 0.f;
      const short8 v00 = *(const short8*)(vbase + (size_t)(y0c * Ws + x0c) * 256);
      const short8 v01 = *(const short8*)(vbase + (size_t)(y0c * Ws + x1c) * 256);
      const short8 v10 = *(const short8*)(vbase + (size_t)(y1c * Ws + x0c) * 256);
      const short8 v11 = *(const short8*)(vbase + (size_t)(y1c * Ws + x1c) * 256);
      const float pw = lg[l * 4 + p] * inv;
      const float w00 = (1.f - wx) * (1.f - wy) * fy0 * fx0 * pw;
      const float w01 = wx * (1.f - wy) * fy0 * fx1 * pw;
      const float w10 = (1.f - wx) * wy * fy1 * fx0 * pw;
      const float w11 = wx * wy * fy1 * fx1 * pw;
#pragma unroll
      for (int e = 0; e < 8; e++) {
        acc[e] = fmaf(w00, bf2f((u16)v00[e]), acc[e]);
        acc[e] = fmaf(w01, bf2f((u16)v01[e]), acc[e]);
        acc[e] = fmaf(w10, bf2f((u16)v10[e]), acc[e]);
        acc[e] = fmaf(w11, bf2f((u16)v11[e]), acc[e]);
      }
    }
  }
  short8 o;
#pragma unroll
  for (int e = 0; e < 8; e++) o[e] = (short)f2bf(acc[e]);
  *(short8*)outp = o;
}

extern "C" void kernel_launch(void* const* d_in, const int* in_sizes, int n_in,
                              void* d_out, int out_size, void* d_ws, size_t ws_size,
                              hipStream_t stream) {
  const float* hidden = (const float*)d_in[0];
  const float* ehs    = (const float*)d_in[1];
  const float* refp   = (const float*)d_in[2];
  const float* vw     = (const float*)d_in[3];
  const float* vb     = (const float*)d_in[4];
  const float* offw   = (const float*)d_in[5];
  const float* offb   = (const float*)d_in[6];
  const float* attnw  = (const float*)d_in[7];
  const float* attnb  = (const float*)d_in[8];
  const float* outw   = (const float*)d_in[9];
  const float* outb   = (const float*)d_in[10];
  float* out = (float*)d_out;

  u16* value = (u16*)d_ws;                 // 34406400 u16
  u16* attn  = value + 34406400;           // 1245184 u16
  u16* WtV   = attn + 1245184;             // 65536
  u16* outwT = WtV + 65536;                // 65536
  float* Wcat  = (float*)(outwT + 65536);  // 73728 f32
  float* bcat  = Wcat + 73728;             // 512
  float* offaw = bcat + 512;               // 1382400

  prep_weights<<<288, 256, 0, stream>>>(vw, offw, attnw, offb, attnb, outw,
                                        WtV, outwT, Wcat, bcat);
  fat_gemm<<<NOFF + 1050, 256, 0, stream>>>(ehs, WtV, vb, value,
                                            hidden, Wcat, bcat, offaw);
  ms_deform_fused<<<608, 256, 0, stream>>>(value, offaw, refp, attn);
  gemm_out_stream<<<38, 256, 0, stream>>>(attn, outwT, outb, out);
}

// Round 8
// 158.147 us; speedup vs baseline: 1.2385x; 1.0870x over previous
//
#include <hip/hip_runtime.h>
#include <math.h>

typedef unsigned short u16;
typedef __attribute__((ext_vector_type(8))) short short8;
typedef __attribute__((ext_vector_type(4))) short short4v;
typedef __attribute__((ext_vector_type(4))) float f32x4;

static __device__ __forceinline__ u16 f2bf(float f) {
  union { float f; unsigned u; } v; v.f = f;
  unsigned u = v.u;
  return (u16)((u + 0x7FFFu + ((u >> 16) & 1u)) >> 16);
}
static __device__ __forceinline__ float bf2f(u16 u) {
  union { unsigned u; float f; } v; v.u = ((unsigned)u) << 16;
  return v.f;
}
static __device__ __forceinline__ f32x4 mfma16(short8 a, short8 b, f32x4 c) {
  return __builtin_amdgcn_mfma_f32_16x16x32_bf16(a, b, c, 0, 0, 0);
}

// ---------------------------------------------------------------------------
// prep: WtV/outwT bf16 transposed [n][k]; Wcat f32 (256x288) + bcat. (proven R4)
// ---------------------------------------------------------------------------
__global__ void prep_weights(const float* __restrict__ vw,
                             const float* __restrict__ offw, const float* __restrict__ attnw,
                             const float* __restrict__ offb, const float* __restrict__ attnb,
                             const float* __restrict__ outw,
                             u16* __restrict__ WtV, u16* __restrict__ outwT,
                             float* __restrict__ Wcat, float* __restrict__ bcat) {
  int idx = blockIdx.x * 256 + threadIdx.x;  // grid 288 -> 73728
  if (idx < 65536) {
    int n = idx >> 8, k = idx & 255;
    WtV[idx] = f2bf(vw[k * 256 + n]);
    outwT[idx] = f2bf(outw[k * 256 + n]);
  }
  if (idx < 73728) {
    int kk = idx / 288, nn = idx % 288;
    Wcat[idx] = (nn < 192) ? offw[kk * 192 + nn] : attnw[kk * 96 + (nn - 192)];
  }
  if (idx < 288) bcat[idx] = (idx < 192) ? offb[idx] : attnb[idx - 192];
}

// ---------------------------------------------------------------------------
// Value GEMM = R4's proven gemm_mfma<0,0> + reg-staged 2-phase pipeline:
// preload tile0 regs; per tile: barrier -> LDS write -> barrier ->
// issue loads(t+1) -> compute(t). Loads(t+1) overlap compute(t); the
// vmcnt(0) drain lands at the NEXT iteration's first barrier, after compute.
// ---------------------------------------------------------------------------
__global__ __launch_bounds__(256) void gemm_value_db(
    const float* __restrict__ A, const u16* __restrict__ Wt,
    const float* __restrict__ bias, u16* __restrict__ C) {
  const int m0 = blockIdx.y * 128, n0 = blockIdx.x * 128;
  __shared__ u16 smem[2 * 128 * 64];
  u16* As = smem;
  u16* Bs = smem + 128 * 64;
  const int tid = threadIdx.x, lane = tid & 63, w = tid >> 6;
  const int wrow = w >> 1, wcol = w & 1;
  const int r8 = tid >> 3, c8 = tid & 7;
  const int swzB = (c8 ^ (r8 & 7)) * 8;
  const int arow_t = tid >> 4, acol4 = (tid & 15) * 4;
  const int aswz = (arow_t & 7) * 8;

  f32x4 acc[4][4];
#pragma unroll
  for (int i = 0; i < 4; i++)
#pragma unroll
    for (int j = 0; j < 4; j++) acc[i][j] = (f32x4){0.f, 0.f, 0.f, 0.f};

  float4 av[8];
  short8 bv[4];
#pragma unroll
  for (int p = 0; p < 8; p++)
    av[p] = *(const float4*)(A + (size_t)(m0 + arow_t + p * 16) * 256 + acol4);
#pragma unroll
  for (int c = 0; c < 4; c++)
    bv[c] = *(const short8*)(Wt + (size_t)(n0 + c * 32 + r8) * 256 + swzB);

#pragma unroll
  for (int t = 0; t < 4; t++) {
    __syncthreads();  // prev tile's LDS reads done; tile-t loads drained here
#pragma unroll
    for (int p = 0; p < 8; p++) {
      short4v sv;
      sv[0] = (short)f2bf(av[p].x);
      sv[1] = (short)f2bf(av[p].y);
      sv[2] = (short)f2bf(av[p].z);
      sv[3] = (short)f2bf(av[p].w);
      *(short4v*)&As[(arow_t + p * 16) * 64 + (acol4 ^ aswz)] = sv;
    }
#pragma unroll
    for (int c = 0; c < 4; c++)
      *(short8*)&Bs[(c * 256 + tid) * 8] = bv[c];
    __syncthreads();

    if (t < 3) {  // next-tile loads fly during compute(t)
      const int k0 = (t + 1) * 64;
#pragma unroll
      for (int p = 0; p < 8; p++)
        av[p] = *(const float4*)(A + (size_t)(m0 + arow_t + p * 16) * 256 + k0 + acol4);
#pragma unroll
      for (int c = 0; c < 4; c++)
        bv[c] = *(const short8*)(Wt + (size_t)(n0 + c * 32 + r8) * 256 + k0 + swzB);
    }

#pragma unroll
    for (int kk = 0; kk < 64; kk += 32) {
      const int kb = kk + ((lane >> 4) << 3);
      short8 af[4], bfr[4];
#pragma unroll
      for (int i = 0; i < 4; i++) {
        const int row = wrow * 64 + i * 16 + (lane & 15);
        af[i] = *(const short8*)&As[row * 64 + (kb ^ ((row & 7) * 8))];
      }
#pragma unroll
      for (int j = 0; j < 4; j++) {
        const int nr = wcol * 64 + j * 16 + (lane & 15);
        bfr[j] = *(const short8*)&Bs[nr * 64 + (kb ^ ((nr & 7) * 8))];
      }
#pragma unroll
      for (int i = 0; i < 4; i++)
#pragma unroll
        for (int j = 0; j < 4; j++)
          acc[i][j] = mfma16(af[i], bfr[j], acc[i][j]);
    }
  }

  __syncthreads();
  u16* Cs = smem;  // 128x128 u16 repack
#pragma unroll
  for (int i = 0; i < 4; i++) {
#pragma unroll
    for (int j = 0; j < 4; j++) {
      const int col = wcol * 64 + j * 16 + (lane & 15);
      const float bc = bias[n0 + col];
#pragma unroll
      for (int r = 0; r < 4; r++) {
        const int row = wrow * 64 + i * 16 + ((lane >> 4) << 2) + r;
        Cs[row * 128 + (col ^ ((row & 7) * 8))] = f2bf(acc[i][j][r] + bc);
      }
    }
  }
  __syncthreads();
#pragma unroll
  for (int p = 0; p < 8; p++) {
    const int row = arow_t + p * 16;
    const int g = (tid & 15) * 8;
    *(short8*)(C + (size_t)(m0 + row) * 256 + n0 + g) =
        *(const short8*)&Cs[row * 128 + (g ^ ((row & 7) * 8))];
  }
}

// ---------------------------------------------------------------------------
// fp32 GEMM for position-critical offsets/logits (proven R1/R4/R6).
// ---------------------------------------------------------------------------
#define BM 128
#define BN 128
#define BK 8
#define TM 8
#define TN 8
__global__ __launch_bounds__(256) void gemm_f32(
    const float* __restrict__ A, const float* __restrict__ W,
    const float* __restrict__ bias, float* __restrict__ C,
    int M, int N, int K) {
  __shared__ float As[BK][BM + 4];
  __shared__ float Bs[BK][BN + 4];
  const int tid = threadIdx.x;
  const int bm = blockIdx.y, bn = blockIdx.x;
  const int tr = tid >> 4, tc = tid & 15;

  float acc[TM][TN];
#pragma unroll
  for (int i = 0; i < TM; i++)
#pragma unroll
    for (int j = 0; j < TN; j++) acc[i][j] = 0.f;

  int arow = bm * BM + (tid >> 1);
  int arow_c = arow < M ? arow : (M - 1);
  const float* Aptr = A + (size_t)arow_c * K + ((tid & 1) << 2);
  int bcol = bn * BN + ((tid & 31) << 2);
  const bool bvalid = bcol < N;
  const float* Wptr = W + (size_t)(tid >> 5) * N + bcol;

  for (int k0 = 0; k0 < K; k0 += BK) {
    float4 av = *(const float4*)(Aptr + k0);
    float4 bv = bvalid ? *(const float4*)(Wptr + (size_t)k0 * N)
                       : make_float4(0.f, 0.f, 0.f, 0.f);
    __syncthreads();
    As[(tid & 1) * 4 + 0][tid >> 1] = av.x;
    As[(tid & 1) * 4 + 1][tid >> 1] = av.y;
    As[(tid & 1) * 4 + 2][tid >> 1] = av.z;
    As[(tid & 1) * 4 + 3][tid >> 1] = av.w;
    *(float4*)&Bs[tid >> 5][(tid & 31) << 2] = bv;
    __syncthreads();
#pragma unroll
    for (int k = 0; k < BK; k++) {
      float ar[TM], br[TN];
      *(float4*)&ar[0] = *(const float4*)&As[k][tr * TM];
      *(float4*)&ar[4] = *(const float4*)&As[k][tr * TM + 4];
      *(float4*)&br[0] = *(const float4*)&Bs[k][tc * TN];
      *(float4*)&br[4] = *(const float4*)&Bs[k][tc * TN + 4];
#pragma unroll
      for (int i = 0; i < TM; i++)
#pragma unroll
        for (int j = 0; j < TN; j++) acc[i][j] = fmaf(ar[i], br[j], acc[i][j]);
    }
  }

#pragma unroll
  for (int i = 0; i < TM; i++) {
    int row = bm * BM + tr * TM + i;
    if (row >= M) continue;
    float* Crow = C + (size_t)row * N;
#pragma unroll
    for (int j = 0; j < TN; j += 4) {
      int col = bn * BN + tc * TN + j;
      if (col < N) {
        float4 o;
        o.x = acc[i][j + 0] + bias[col + 0];
        o.y = acc[i][j + 1] + bias[col + 1];
        o.z = acc[i][j + 2] + bias[col + 2];
        o.w = acc[i][j + 3] + bias[col + 3];
        *(float4*)(Crow + col) = o;
      }
    }
  }
}

// ---------------------------------------------------------------------------
// Branch-free sampling, 4 channels/lane, 1 query/wave (proven R4). grid 1216.
// ---------------------------------------------------------------------------
__global__ __launch_bounds__(256) void ms_deform_fused(
    const u16* __restrict__ value,    // (B*8400, 256) bf16
    const float* __restrict__ offaw,  // (4800, 288)
    const float* __restrict__ refp,   // (16,300,3,4)
    u16* __restrict__ attn_out) {     // (4864, 256) bf16
  const int q_local = threadIdx.x >> 6;
  const int bq = blockIdx.x * 4 + q_local;   // 0..4863
  const int h = (threadIdx.x >> 3) & 7;
  const int d4 = (threadIdx.x & 7) * 4;
  u16* outp = attn_out + (size_t)bq * 256 + h * 32 + d4;
  if (bq >= 4800) {
    short4v z = {0, 0, 0, 0};
    *(short4v*)outp = z;
    return;
  }
  const int b = bq / 300;
  const float* row = offaw + (size_t)bq * 288;

  float lg[12];
#pragma unroll
  for (int j = 0; j < 12; j++) lg[j] = row[192 + h * 12 + j];
  float m = lg[0];
#pragma unroll
  for (int j = 1; j < 12; j++) m = fmaxf(m, lg[j]);
  float s = 0.f;
#pragma unroll
  for (int j = 0; j < 12; j++) { lg[j] = __expf(lg[j] - m); s += lg[j]; }
  const float inv = 1.f / s;

  const int lvlW[3] = {80, 40, 20};
  const int lvlS[3] = {0, 6400, 8000};
  const float* ref = refp + (size_t)bq * 12;
  float acc0 = 0.f, acc1 = 0.f, acc2 = 0.f, acc3 = 0.f;

#pragma unroll
  for (int l = 0; l < 3; l++) {
    const int Ws = lvlW[l];
    const float r0 = ref[l * 4 + 0], r1 = ref[l * 4 + 1];
    const float r2 = ref[l * 4 + 2], r3 = ref[l * 4 + 3];
    const u16* vbase = value + ((size_t)(b * 8400 + lvlS[l]) * 256) + h * 32 + d4;
#pragma unroll
    for (int p = 0; p < 4; p++) {
      const float ox = row[h * 24 + l * 8 + p * 2 + 0];
      const float oy = row[h * 24 + l * 8 + p * 2 + 1];
      const float x = (r0 + ox * 0.125f * r2) * (float)Ws - 0.5f;
      const float y = (r1 + oy * 0.125f * r3) * (float)Ws - 0.5f;
      const float x0f = floorf(x), y0f = floorf(y);
      const float wx = x - x0f, wy = y - y0f;
      const int x0 = (int)x0f, y0 = (int)y0f;
      const int x0c = min(max(x0, 0), Ws - 1), x1c = min(max(x0 + 1, 0), Ws - 1);
      const int y0c = min(max(y0, 0), Ws - 1), y1c = min(max(y0 + 1, 0), Ws - 1);
      const float fx0 = ((unsigned)x0 < (unsigned)Ws) ? 1.f : 0.f;
      const float fx1 = ((unsigned)(x0 + 1) < (unsigned)Ws) ? 1.f : 0.f;
      const float fy0 = ((unsigned)y0 < (unsigned)Ws) ? 1.f : 0.f;
      const float fy1 = ((unsigned)(y0 + 1) < (unsigned)Ws) ? 1.f : 0.f;
      const short4v v00 = *(const short4v*)(vbase + (size_t)(y0c * Ws + x0c) * 256);
      const short4v v01 = *(const short4v*)(vbase + (size_t)(y0c * Ws + x1c) * 256);
      const short4v v10 = *(const short4v*)(vbase + (size_t)(y1c * Ws + x0c) * 256);
      const short4v v11 = *(const short4v*)(vbase + (size_t)(y1c * Ws + x1c) * 256);
      const float pw = lg[l * 4 + p] * inv;
      const float w00 = (1.f - wx) * (1.f - wy) * fy0 * fx0 * pw;
      const float w01 = wx * (1.f - wy) * fy0 * fx1 * pw;
      const float w10 = (1.f - wx) * wy * fy1 * fx0 * pw;
      const float w11 = wx * wy * fy1 * fx1 * pw;
      acc0 = fmaf(w00, bf2f((u16)v00[0]), acc0);
      acc1 = fmaf(w00, bf2f((u16)v00[1]), acc1);
      acc2 = fmaf(w00, bf2f((u16)v00[2]), acc2);
      acc3 = fmaf(w00, bf2f((u16)v00[3]), acc3);
      acc0 = fmaf(w01, bf2f((u16)v01[0]), acc0);
      acc1 = fmaf(w01, bf2f((u16)v01[1]), acc1);
      acc2 = fmaf(w01, bf2f((u16)v01[2]), acc2);
      acc3 = fmaf(w01, bf2f((u16)v01[3]), acc3);
      acc0 = fmaf(w10, bf2f((u16)v10[0]), acc0);
      acc1 = fmaf(w10, bf2f((u16)v10[1]), acc1);
      acc2 = fmaf(w10, bf2f((u16)v10[2]), acc2);
      acc3 = fmaf(w10, bf2f((u16)v10[3]), acc3);
      acc0 = fmaf(w11, bf2f((u16)v11[0]), acc0);
      acc1 = fmaf(w11, bf2f((u16)v11[1]), acc1);
      acc2 = fmaf(w11, bf2f((u16)v11[2]), acc2);
      acc3 = fmaf(w11, bf2f((u16)v11[3]), acc3);
    }
  }
  short4v o;
  o[0] = (short)f2bf(acc0);
  o[1] = (short)f2bf(acc1);
  o[2] = (short)f2bf(acc2);
  o[3] = (short)f2bf(acc3);
  *(short4v*)outp = o;
}

// ---------------------------------------------------------------------------
// Out-proj streaming GEMM: A bf16 (4864 rows padded), C f32 (4800,256). Proven R6.
// ---------------------------------------------------------------------------
__global__ __launch_bounds__(256) void gemm_out_stream(
    const u16* __restrict__ A, const u16* __restrict__ Wt,
    const float* __restrict__ bias, float* __restrict__ C) {
  const int tid = threadIdx.x, lane = tid & 63, w = tid >> 6;
  const int m0 = (blockIdx.x * 2 + (w >> 1)) * 64;
  const int n0 = (w & 1) * 128;
  const int r16 = lane & 15, kq = lane >> 4, kh8 = kq * 8;

  f32x4 acc[4][8];
#pragma unroll
  for (int i = 0; i < 4; i++)
#pragma unroll
    for (int j = 0; j < 8; j++) acc[i][j] = (f32x4){0.f, 0.f, 0.f, 0.f};

  const u16* ab = A + (size_t)(m0 + r16) * 256 + kh8;
  const u16* bb = Wt + (size_t)(n0 + r16) * 256 + kh8;

#pragma unroll 2
  for (int ks = 0; ks < 8; ks++) {
    const int kk = ks * 32;
    short8 bfr[8], afr[4];
#pragma unroll
    for (int j = 0; j < 8; j++)
      bfr[j] = *(const short8*)(bb + (size_t)(j * 16) * 256 + kk);
#pragma unroll
    for (int i = 0; i < 4; i++)
      afr[i] = *(const short8*)(ab + (size_t)(i * 16) * 256 + kk);
#pragma unroll
    for (int i = 0; i < 4; i++)
#pragma unroll
      for (int j = 0; j < 8; j++)
        acc[i][j] = mfma16(afr[i], bfr[j], acc[i][j]);
  }

  if (m0 >= 4800) return;
#pragma unroll
  for (int i = 0; i < 4; i++)
#pragma unroll
    for (int j = 0; j < 8; j++) {
      const int col = n0 + j * 16 + r16;
      const float bc = bias[col];
#pragma unroll
      for (int r = 0; r < 4; r++) {
        const int row = m0 + i * 16 + kq * 4 + r;
        C[(size_t)row * 256 + col] = acc[i][j][r] + bc;
      }
    }
}

extern "C" void kernel_launch(void* const* d_in, const int* in_sizes, int n_in,
                              void* d_out, int out_size, void* d_ws, size_t ws_size,
                              hipStream_t stream) {
  const float* hidden = (const float*)d_in[0];
  const float* ehs    = (const float*)d_in[1];
  const float* refp   = (const float*)d_in[2];
  const float* vw     = (const float*)d_in[3];
  const float* vb     = (const float*)d_in[4];
  const float* offw   = (const float*)d_in[5];
  const float* offb   = (const float*)d_in[6];
  const float* attnw  = (const float*)d_in[7];
  const float* attnb  = (const float*)d_in[8];
  const float* outw   = (const float*)d_in[9];
  const float* outb   = (const float*)d_in[10];
  float* out = (float*)d_out;

  u16* value = (u16*)d_ws;                 // 34406400 u16
  u16* attn  = value + 34406400;           // 1245184 u16
  u16* WtV   = attn + 1245184;             // 65536
  u16* outwT = WtV + 65536;                // 65536
  float* Wcat  = (float*)(outwT + 65536);  // 73728 f32
  float* bcat  = Wcat + 73728;             // 512
  float* offaw = bcat + 512;               // 1382400

  prep_weights<<<288, 256, 0, stream>>>(vw, offw, attnw, offb, attnb, outw,
                                        WtV, outwT, Wcat, bcat);
  gemm_f32<<<dim3(3, 38), 256, 0, stream>>>(hidden, Wcat, bcat, offaw, 4800, 288, 256);
  gemm_value_db<<<dim3(2, 1050), 256, 0, stream>>>(ehs, WtV, vb, value);
  ms_deform_fused<<<1216, 256, 0, stream>>>(value, offaw, refp, attn);
  gemm_out_stream<<<38, 256, 0, stream>>>(attn, outwT, outb, out);
}

// Round 9
// 152.308 us; speedup vs baseline: 1.2860x; 1.0383x over previous
//
#include <hip/hip_runtime.h>
#include <math.h>

typedef unsigned short u16;
typedef __attribute__((ext_vector_type(8))) short short8;
typedef __attribute__((ext_vector_type(4))) short short4v;
typedef __attribute__((ext_vector_type(4))) float f32x4;

static __device__ __forceinline__ u16 f2bf(float f) {
  union { float f; unsigned u; } v; v.f = f;
  unsigned u = v.u;
  return (u16)((u + 0x7FFFu + ((u >> 16) & 1u)) >> 16);
}
static __device__ __forceinline__ float bf2f(u16 u) {
  union { unsigned u; float f; } v; v.u = ((unsigned)u) << 16;
  return v.f;
}
static __device__ __forceinline__ f32x4 mfma16(short8 a, short8 b, f32x4 c) {
  return __builtin_amdgcn_mfma_f32_16x16x32_bf16(a, b, c, 0, 0, 0);
}

// ---------------------------------------------------------------------------
// prep: WtV/outwT bf16 transposed [n][k]; Wcat f32 (256x288) + bcat. (proven)
// ---------------------------------------------------------------------------
__global__ void prep_weights(const float* __restrict__ vw,
                             const float* __restrict__ offw, const float* __restrict__ attnw,
                             const float* __restrict__ offb, const float* __restrict__ attnb,
                             const float* __restrict__ outw,
                             u16* __restrict__ WtV, u16* __restrict__ outwT,
                             float* __restrict__ Wcat, float* __restrict__ bcat) {
  int idx = blockIdx.x * 256 + threadIdx.x;  // grid 288 -> 73728
  if (idx < 65536) {
    int n = idx >> 8, k = idx & 255;
    WtV[idx] = f2bf(vw[k * 256 + n]);
    outwT[idx] = f2bf(outw[k * 256 + n]);
  }
  if (idx < 73728) {
    int kk = idx / 288, nn = idx % 288;
    Wcat[idx] = (nn < 192) ? offw[kk * 192 + nn] : attnw[kk * 96 + (nn - 192)];
  }
  if (idx < 288) bcat[idx] = (idx < 192) ? offb[idx] : attnb[idx - 192];
}

// ---------------------------------------------------------------------------
// Value GEMM, BK=32: 8 K-steps of 24KB loads each (burst-smoothing vs BK=64's
// 4x48KB). 2-phase reg prefetch (proven R8). 128x128 tile, 4 waves.
// A-stage: 8 lanes/row (full 128B lines); XOR swizzle (row&3)*8 within 32 cols.
// Epilogue/acc mappings byte-identical to proven R4. LDS 32KB (Cs repack).
// ---------------------------------------------------------------------------
__global__ __launch_bounds__(256) void gemm_value_bk32(
    const float* __restrict__ A, const u16* __restrict__ Wt,
    const float* __restrict__ bias, u16* __restrict__ C) {
  const int m0 = blockIdx.y * 128, n0 = blockIdx.x * 128;
  __shared__ u16 smem[16384];      // 32 KiB: As 4096 + Bs 4096 (steps); Cs 16384 (epilogue)
  u16* As = smem;                  // [128][32] bf16
  u16* Bs = smem + 4096;           // [128][32] bf16
  const int tid = threadIdx.x, lane = tid & 63, w = tid >> 6;
  const int wrow = w >> 1, wcol = w & 1;
  // A staging: 8 threads/row, float4 each, 4 row-passes
  const int ar = tid >> 3;               // 0..31
  const int ac4 = (tid & 7) * 4;         // 0..28
  // B staging: 2 threads/row, 2x short8 each
  const int bn = tid >> 1;               // 0..127
  const int bc16 = (tid & 1) * 16;       // 0 or 16
  const int bswz = (bn & 3) * 8;

  f32x4 acc[4][4];
#pragma unroll
  for (int i = 0; i < 4; i++)
#pragma unroll
    for (int j = 0; j < 4; j++) acc[i][j] = (f32x4){0.f, 0.f, 0.f, 0.f};

  float4 av[4];
  short8 bv[2];
#pragma unroll
  for (int p = 0; p < 4; p++)
    av[p] = *(const float4*)(A + (size_t)(m0 + ar + p * 32) * 256 + ac4);
#pragma unroll
  for (int j = 0; j < 2; j++)
    bv[j] = *(const short8*)(Wt + (size_t)(n0 + bn) * 256 + ((bc16 + 8 * j) ^ bswz));

#pragma unroll
  for (int t = 0; t < 8; t++) {
    __syncthreads();  // prev step's LDS reads done; step-t loads drained
#pragma unroll
    for (int p = 0; p < 4; p++) {
      const int row = ar + p * 32;
      short4v sv;
      sv[0] = (short)f2bf(av[p].x);
      sv[1] = (short)f2bf(av[p].y);
      sv[2] = (short)f2bf(av[p].z);
      sv[3] = (short)f2bf(av[p].w);
      *(short4v*)&As[row * 32 + (ac4 ^ ((row & 3) * 8))] = sv;
    }
#pragma unroll
    for (int j = 0; j < 2; j++)
      *(short8*)&Bs[bn * 32 + bc16 + 8 * j] = bv[j];
    __syncthreads();

    if (t < 7) {  // next-step loads fly during compute(t)
      const int k0 = (t + 1) * 32;
#pragma unroll
      for (int p = 0; p < 4; p++)
        av[p] = *(const float4*)(A + (size_t)(m0 + ar + p * 32) * 256 + k0 + ac4);
#pragma unroll
      for (int j = 0; j < 2; j++)
        bv[j] = *(const short8*)(Wt + (size_t)(n0 + bn) * 256 + k0 + ((bc16 + 8 * j) ^ bswz));
    }

    const int kb = (lane >> 4) * 8;  // k-slot within 32
    short8 af[4], bfr[4];
#pragma unroll
    for (int i = 0; i < 4; i++) {
      const int row = wrow * 64 + i * 16 + (lane & 15);
      af[i] = *(const short8*)&As[row * 32 + (kb ^ ((row & 3) * 8))];
    }
#pragma unroll
    for (int j = 0; j < 4; j++) {
      const int nr = wcol * 64 + j * 16 + (lane & 15);
      bfr[j] = *(const short8*)&Bs[nr * 32 + (kb ^ ((nr & 3) * 8))];
    }
#pragma unroll
    for (int i = 0; i < 4; i++)
#pragma unroll
      for (int j = 0; j < 4; j++)
        acc[i][j] = mfma16(af[i], bfr[j], acc[i][j]);
  }

  // epilogue: LDS repack -> dwordx4 stores (byte-identical to proven R4)
  __syncthreads();
  u16* Cs = smem;  // 128x128 u16
#pragma unroll
  for (int i = 0; i < 4; i++) {
#pragma unroll
    for (int j = 0; j < 4; j++) {
      const int col = wcol * 64 + j * 16 + (lane & 15);
      const float bc = bias[n0 + col];
#pragma unroll
      for (int r = 0; r < 4; r++) {
        const int row = wrow * 64 + i * 16 + ((lane >> 4) << 2) + r;
        Cs[row * 128 + (col ^ ((row & 7) * 8))] = f2bf(acc[i][j][r] + bc);
      }
    }
  }
  __syncthreads();
#pragma unroll
  for (int p = 0; p < 8; p++) {
    const int row = (tid >> 4) + p * 16;
    const int g = (tid & 15) * 8;
    *(short8*)(C + (size_t)(m0 + row) * 256 + n0 + g) =
        *(const short8*)&Cs[row * 128 + (g ^ ((row & 7) * 8))];
  }
}

// ---------------------------------------------------------------------------
// fp32 GEMM for position-critical offsets/logits (proven R1/R4/R6).
// ---------------------------------------------------------------------------
#define BM 128
#define BN 128
#define BK 8
#define TM 8
#define TN 8
__global__ __launch_bounds__(256) void gemm_f32(
    const float* __restrict__ A, const float* __restrict__ W,
    const float* __restrict__ bias, float* __restrict__ C,
    int M, int N, int K) {
  __shared__ float As[BK][BM + 4];
  __shared__ float Bs[BK][BN + 4];
  const int tid = threadIdx.x;
  const int bm = blockIdx.y, bn = blockIdx.x;
  const int tr = tid >> 4, tc = tid & 15;

  float acc[TM][TN];
#pragma unroll
  for (int i = 0; i < TM; i++)
#pragma unroll
    for (int j = 0; j < TN; j++) acc[i][j] = 0.f;

  int arow = bm * BM + (tid >> 1);
  int arow_c = arow < M ? arow : (M - 1);
  const float* Aptr = A + (size_t)arow_c * K + ((tid & 1) << 2);
  int bcol = bn * BN + ((tid & 31) << 2);
  const bool bvalid = bcol < N;
  const float* Wptr = W + (size_t)(tid >> 5) * N + bcol;

  for (int k0 = 0; k0 < K; k0 += BK) {
    float4 av = *(const float4*)(Aptr + k0);
    float4 bv = bvalid ? *(const float4*)(Wptr + (size_t)k0 * N)
                       : make_float4(0.f, 0.f, 0.f, 0.f);
    __syncthreads();
    As[(tid & 1) * 4 + 0][tid >> 1] = av.x;
    As[(tid & 1) * 4 + 1][tid >> 1] = av.y;
    As[(tid & 1) * 4 + 2][tid >> 1] = av.z;
    As[(tid & 1) * 4 + 3][tid >> 1] = av.w;
    *(float4*)&Bs[tid >> 5][(tid & 31) << 2] = bv;
    __syncthreads();
#pragma unroll
    for (int k = 0; k < BK; k++) {
      float ar[TM], br[TN];
      *(float4*)&ar[0] = *(const float4*)&As[k][tr * TM];
      *(float4*)&ar[4] = *(const float4*)&As[k][tr * TM + 4];
      *(float4*)&br[0] = *(const float4*)&Bs[k][tc * TN];
      *(float4*)&br[4] = *(const float4*)&Bs[k][tc * TN + 4];
#pragma unroll
      for (int i = 0; i < TM; i++)
#pragma unroll
        for (int j = 0; j < TN; j++) acc[i][j] = fmaf(ar[i], br[j], acc[i][j]);
    }
  }

#pragma unroll
  for (int i = 0; i < TM; i++) {
    int row = bm * BM + tr * TM + i;
    if (row >= M) continue;
    float* Crow = C + (size_t)row * N;
#pragma unroll
    for (int j = 0; j < TN; j += 4) {
      int col = bn * BN + tc * TN + j;
      if (col < N) {
        float4 o;
        o.x = acc[i][j + 0] + bias[col + 0];
        o.y = acc[i][j + 1] + bias[col + 1];
        o.z = acc[i][j + 2] + bias[col + 2];
        o.w = acc[i][j + 3] + bias[col + 3];
        *(float4*)(Crow + col) = o;
      }
    }
  }
}

// ---------------------------------------------------------------------------
// Branch-free sampling, 4 channels/lane, 1 query/wave (proven R4), with
// XCD-aware block swizzle: blockIdx%8 = XCD slot P serves batches {2P,2P+1}
// so each XCD's L2 caches only its 2 batches' value slice (8.6 MB).
// grid 1216 = 8 x 152: t<150 -> bq0 = P*600 + 4t; t in {150,151} -> pad rows.
// ---------------------------------------------------------------------------
__global__ __launch_bounds__(256) void ms_deform_fused(
    const u16* __restrict__ value,    // (B*8400, 256) bf16
    const float* __restrict__ offaw,  // (4800, 288)
    const float* __restrict__ refp,   // (16,300,3,4)
    u16* __restrict__ attn_out) {     // (4864, 256) bf16
  const int P = blockIdx.x & 7;
  const int t = blockIdx.x >> 3;     // 0..151
  int bq0;
  if (t < 150) bq0 = P * 600 + t * 4;
  else bq0 = 4800 + (P * 2 + (t - 150)) * 4;
  const int q_local = threadIdx.x >> 6;
  const int bq = bq0 + q_local;
  const int h = (threadIdx.x >> 3) & 7;
  const int d4 = (threadIdx.x & 7) * 4;
  u16* outp = attn_out + (size_t)bq * 256 + h * 32 + d4;
  if (bq >= 4800) {
    short4v z = {0, 0, 0, 0};
    *(short4v*)outp = z;
    return;
  }
  const int b = bq / 300;
  const float* row = offaw + (size_t)bq * 288;

  float lg[12];
#pragma unroll
  for (int j = 0; j < 12; j++) lg[j] = row[192 + h * 12 + j];
  float m = lg[0];
#pragma unroll
  for (int j = 1; j < 12; j++) m = fmaxf(m, lg[j]);
  float s = 0.f;
#pragma unroll
  for (int j = 0; j < 12; j++) { lg[j] = __expf(lg[j] - m); s += lg[j]; }
  const float inv = 1.f / s;

  const int lvlW[3] = {80, 40, 20};
  const int lvlS[3] = {0, 6400, 8000};
  const float* ref = refp + (size_t)bq * 12;
  float acc0 = 0.f, acc1 = 0.f, acc2 = 0.f, acc3 = 0.f;

#pragma unroll
  for (int l = 0; l < 3; l++) {
    const int Ws = lvlW[l];
    const float r0 = ref[l * 4 + 0], r1 = ref[l * 4 + 1];
    const float r2 = ref[l * 4 + 2], r3 = ref[l * 4 + 3];
    const u16* vbase = value + ((size_t)(b * 8400 + lvlS[l]) * 256) + h * 32 + d4;
#pragma unroll
    for (int p = 0; p < 4; p++) {
      const float ox = row[h * 24 + l * 8 + p * 2 + 0];
      const float oy = row[h * 24 + l * 8 + p * 2 + 1];
      const float x = (r0 + ox * 0.125f * r2) * (float)Ws - 0.5f;
      const float y = (r1 + oy * 0.125f * r3) * (float)Ws - 0.5f;
      const float x0f = floorf(x), y0f = floorf(y);
      const float wx = x - x0f, wy = y - y0f;
      const int x0 = (int)x0f, y0 = (int)y0f;
      const int x0c = min(max(x0, 0), Ws - 1), x1c = min(max(x0 + 1, 0), Ws - 1);
      const int y0c = min(max(y0, 0), Ws - 1), y1c = min(max(y0 + 1, 0), Ws - 1);
      const float fx0 = ((unsigned)x0 < (unsigned)Ws) ? 1.f : 0.f;
      const float fx1 = ((unsigned)(x0 + 1) < (unsigned)Ws) ? 1.f : 0.f;
      const float fy0 = ((unsigned)y0 < (unsigned)Ws) ? 1.f : 0.f;
      const float fy1 = ((unsigned)(y0 + 1) < (unsigned)Ws) ? 1.f : 0.f;
      const short4v v00 = *(const short4v*)(vbase + (size_t)(y0c * Ws + x0c) * 256);
      const short4v v01 = *(const short4v*)(vbase + (size_t)(y0c * Ws + x1c) * 256);
      const short4v v10 = *(const short4v*)(vbase + (size_t)(y1c * Ws + x0c) * 256);
      const short4v v11 = *(const short4v*)(vbase + (size_t)(y1c * Ws + x1c) * 256);
      const float pw = lg[l * 4 + p] * inv;
      const float w00 = (1.f - wx) * (1.f - wy) * fy0 * fx0 * pw;
      const float w01 = wx * (1.f - wy) * fy0 * fx1 * pw;
      const float w10 = (1.f - wx) * wy * fy1 * fx0 * pw;
      const float w11 = wx * wy * fy1 * fx1 * pw;
      acc0 = fmaf(w00, bf2f((u16)v00[0]), acc0);
      acc1 = fmaf(w00, bf2f((u16)v00[1]), acc1);
      acc2 = fmaf(w00, bf2f((u16)v00[2]), acc2);
      acc3 = fmaf(w00, bf2f((u16)v00[3]), acc3);
      acc0 = fmaf(w01, bf2f((u16)v01[0]), acc0);
      acc1 = fmaf(w01, bf2f((u16)v01[1]), acc1);
      acc2 = fmaf(w01, bf2f((u16)v01[2]), acc2);
      acc3 = fmaf(w01, bf2f((u16)v01[3]), acc3);
      acc0 = fmaf(w10, bf2f((u16)v10[0]), acc0);
      acc1 = fmaf(w10, bf2f((u16)v10[1]), acc1);
      acc2 = fmaf(w10, bf2f((u16)v10[2]), acc2);
      acc3 = fmaf(w10, bf2f((u16)v10[3]), acc3);
      acc0 = fmaf(w11, bf2f((u16)v11[0]), acc0);
      acc1 = fmaf(w11, bf2f((u16)v11[1]), acc1);
      acc2 = fmaf(w11, bf2f((u16)v11[2]), acc2);
      acc3 = fmaf(w11, bf2f((u16)v11[3]), acc3);
    }
  }
  short4v o;
  o[0] = (short)f2bf(acc0);
  o[1] = (short)f2bf(acc1);
  o[2] = (short)f2bf(acc2);
  o[3] = (short)f2bf(acc3);
  *(short4v*)outp = o;
}

// ---------------------------------------------------------------------------
// Out-proj streaming GEMM: A bf16 (4864 rows padded), C f32 (4800,256). Proven R6.
// ---------------------------------------------------------------------------
__global__ __launch_bounds__(256) void gemm_out_stream(
    const u16* __restrict__ A, const u16* __restrict__ Wt,
    const float* __restrict__ bias, float* __restrict__ C) {
  const int tid = threadIdx.x, lane = tid & 63, w = tid >> 6;
  const int m0 = (blockIdx.x * 2 + (w >> 1)) * 64;
  const int n0 = (w & 1) * 128;
  const int r16 = lane & 15, kq = lane >> 4, kh8 = kq * 8;

  f32x4 acc[4][8];
#pragma unroll
  for (int i = 0; i < 4; i++)
#pragma unroll
    for (int j = 0; j < 8; j++) acc[i][j] = (f32x4){0.f, 0.f, 0.f, 0.f};

  const u16* ab = A + (size_t)(m0 + r16) * 256 + kh8;
  const u16* bb = Wt + (size_t)(n0 + r16) * 256 + kh8;

#pragma unroll 2
  for (int ks = 0; ks < 8; ks++) {
    const int kk = ks * 32;
    short8 bfr[8], afr[4];
#pragma unroll
    for (int j = 0; j < 8; j++)
      bfr[j] = *(const short8*)(bb + (size_t)(j * 16) * 256 + kk);
#pragma unroll
    for (int i = 0; i < 4; i++)
      afr[i] = *(const short8*)(ab + (size_t)(i * 16) * 256 + kk);
#pragma unroll
    for (int i = 0; i < 4; i++)
#pragma unroll
      for (int j = 0; j < 8; j++)
        acc[i][j] = mfma16(afr[i], bfr[j], acc[i][j]);
  }

  if (m0 >= 4800) return;
#pragma unroll
  for (int i = 0; i < 4; i++)
#pragma unroll
    for (int j = 0; j < 8; j++) {
      const int col = n0 + j * 16 + r16;
      const float bc = bias[col];
#pragma unroll
      for (int r = 0; r < 4; r++) {
        const int row = m0 + i * 16 + kq * 4 + r;
        C[(size_t)row * 256 + col] = acc[i][j][r] + bc;
      }
    }
}

extern "C" void kernel_launch(void* const* d_in, const int* in_sizes, int n_in,
                              void* d_out, int out_size, void* d_ws, size_t ws_size,
                              hipStream_t stream) {
  const float* hidden = (const float*)d_in[0];
  const float* ehs    = (const float*)d_in[1];
  const float* refp   = (const float*)d_in[2];
  const float* vw     = (const float*)d_in[3];
  const float* vb     = (const float*)d_in[4];
  const float* offw   = (const float*)d_in[5];
  const float* offb   = (const float*)d_in[6];
  const float* attnw  = (const float*)d_in[7];
  const float* attnb  = (const float*)d_in[8];
  const float* outw   = (const float*)d_in[9];
  const float* outb   = (const float*)d_in[10];
  float* out = (float*)d_out;

  u16* value = (u16*)d_ws;                 // 34406400 u16
  u16* attn  = value + 34406400;           // 1245184 u16
  u16* WtV   = attn + 1245184;             // 65536
  u16* outwT = WtV + 65536;                // 65536
  float* Wcat  = (float*)(outwT + 65536);  // 73728 f32
  float* bcat  = Wcat + 73728;             // 512
  float* offaw = bcat + 512;               // 1382400

  prep_weights<<<288, 256, 0, stream>>>(vw, offw, attnw, offb, attnb, outw,
                                        WtV, outwT, Wcat, bcat);
  gemm_f32<<<dim3(3, 38), 256, 0, stream>>>(hidden, Wcat, bcat, offaw, 4800, 288, 256);
  gemm_value_bk32<<<dim3(2, 1050), 256, 0, stream>>>(ehs, WtV, vb, value);
  ms_deform_fused<<<1216, 256, 0, stream>>>(value, offaw, refp, attn);
  gemm_out_stream<<<38, 256, 0, stream>>>(attn, outwT, outb, out);
}